// Round 1
// baseline (661.369 us; speedup 1.0000x reference)
//
#include <hip/hip_runtime.h>
#include <hip/hip_bf16.h>

#define T_LEN 2048
#define D_DIM 1024
#define H_NUM 16
#define DK 64

typedef unsigned short u16;
typedef __bf16 bf16x8 __attribute__((ext_vector_type(8)));
typedef float f32x4 __attribute__((ext_vector_type(4)));
typedef u16 u16x8 __attribute__((ext_vector_type(8)));

#define AS1 __attribute__((address_space(1)))
#define AS3 __attribute__((address_space(3)))

__device__ __forceinline__ u16 f2bf(float f) {
    unsigned u = __builtin_bit_cast(unsigned, f);
    unsigned rounding = 0x7FFFu + ((u >> 16) & 1u);
    return (u16)((u + rounding) >> 16);
}

// ---------------- f32 -> bf16 conversion (8 elems / thread) ----------------
__global__ __launch_bounds__(256) void cvt_bf16(const float* __restrict__ in,
                                                u16* __restrict__ out, int n8) {
    int i = blockIdx.x * blockDim.x + threadIdx.x;
    if (i >= n8) return;
    const float4* p = (const float4*)in + (size_t)i * 2;
    float4 a = p[0], b = p[1];
    u16x8 r;
    r[0] = f2bf(a.x); r[1] = f2bf(a.y); r[2] = f2bf(a.z); r[3] = f2bf(a.w);
    r[4] = f2bf(b.x); r[5] = f2bf(b.y); r[6] = f2bf(b.z); r[7] = f2bf(b.w);
    *((u16x8*)out + i) = r;
}

// ---------------- GEMM: C[M,N] = A[M,K] * W[N,K]^T + bias ----------------
// MODE 0: f32 row-major store (final projection)
// MODE 1: bf16 store permuted to [B, H, T, DK] (qkv projections)
template <int MODE>
__global__ __launch_bounds__(256) void gemm_bt(const u16* __restrict__ A,
                                               const u16* __restrict__ W,
                                               const float* __restrict__ bias,
                                               void* __restrict__ Cout,
                                               int M, int N, int K) {
    __shared__ u16 lA[128 * 32];
    __shared__ u16 lB[128 * 32];
    const int tid = threadIdx.x;
    const int w = tid >> 6, lane = tid & 63;
    const int tm = blockIdx.x * 128;
    const int tn = blockIdx.y * 128;
    const int wm = (w >> 1) * 64, wn = (w & 1) * 64;
    const int kgrp = (lane >> 4) * 8;

    f32x4 acc[4][4] = {};

    for (int k0 = 0; k0 < K; k0 += 32) {
        __syncthreads();
#pragma unroll
        for (int r = 0; r < 2; ++r) {
            int c = r * 256 + tid;
            int row = c >> 2, col = (c & 3) * 8;
            const u16* ga = A + (size_t)(tm + row) * K + k0 + col;
            const u16* gb = W + (size_t)(tn + row) * K + k0 + col;
            __builtin_amdgcn_global_load_lds((AS1 const void*)ga,
                (AS3 void*)(lA + (size_t)(r * 256 + w * 64) * 8), 16, 0, 0);
            __builtin_amdgcn_global_load_lds((AS1 const void*)gb,
                (AS3 void*)(lB + (size_t)(r * 256 + w * 64) * 8), 16, 0, 0);
        }
        __syncthreads();

        bf16x8 af[4], bfr[4];
#pragma unroll
        for (int i = 0; i < 4; ++i) {
            af[i]  = *(const bf16x8*)(lA + (wm + i * 16 + (lane & 15)) * 32 + kgrp);
            bfr[i] = *(const bf16x8*)(lB + (wn + i * 16 + (lane & 15)) * 32 + kgrp);
        }
#pragma unroll
        for (int mi = 0; mi < 4; ++mi)
#pragma unroll
            for (int ni = 0; ni < 4; ++ni)
                acc[mi][ni] = __builtin_amdgcn_mfma_f32_16x16x32_bf16(
                    af[mi], bfr[ni], acc[mi][ni], 0, 0, 0);
    }

    const int crow0 = (lane >> 4) * 4;
    const int ccol = lane & 15;
#pragma unroll
    for (int mi = 0; mi < 4; ++mi) {
#pragma unroll
        for (int ni = 0; ni < 4; ++ni) {
            int n = tn + wn + ni * 16 + ccol;
            float bv = bias[n];
#pragma unroll
            for (int r = 0; r < 4; ++r) {
                int m = tm + wm + mi * 16 + crow0 + r;
                float val = acc[mi][ni][r] + bv;
                if (MODE == 0) {
                    ((float*)Cout)[(size_t)m * N + n] = val;
                } else {
                    int b = m >> 11, t = m & (T_LEN - 1);
                    int h = n >> 6, d = n & 63;
                    ((u16*)Cout)[((size_t)(b * H_NUM + h) * T_LEN + t) * DK + d] = f2bf(val);
                }
            }
        }
    }
}

// ---------------- Flash attention, causal ----------------
// grid: (T/64, B*H), block 256. Wave w owns Q rows [q0+w*16, q0+w*16+16).
__global__ __launch_bounds__(256) void attn_fwd(const u16* __restrict__ q,
                                                const u16* __restrict__ k,
                                                const u16* __restrict__ v,
                                                u16* __restrict__ o) {
    __shared__ u16 lK[32 * 64];   // [key][d]
    __shared__ u16 lVT[64 * 32];  // [d][key]
    __shared__ u16 lP[4][16 * 32];

    const int tid = threadIdx.x, w = tid >> 6, lane = tid & 63;
    const int bh = blockIdx.y;
    const int q0 = blockIdx.x * 64;
    const u16* qb = q + (size_t)bh * T_LEN * DK;
    const u16* kb = k + (size_t)bh * T_LEN * DK;
    const u16* vb = v + (size_t)bh * T_LEN * DK;

    const int kgrp = (lane >> 4) * 8;
    const int ccol = lane & 15;
    const int arow = q0 + w * 16 + (lane & 15);   // A-frag row (q index)
    const int crow = q0 + w * 16 + (lane >> 4) * 4;  // C rows base

    bf16x8 qa[2];
    qa[0] = *(const bf16x8*)(qb + (size_t)arow * DK + kgrp);
    qa[1] = *(const bf16x8*)(qb + (size_t)arow * DK + 32 + kgrp);

    f32x4 oacc[4] = {};
    float mrow[4], lrow[4];
#pragma unroll
    for (int r = 0; r < 4; ++r) { mrow[r] = -1e30f; lrow[r] = 0.f; }

    const int ntiles = (q0 + 64) >> 5;
    for (int kt = 0; kt < ntiles; ++kt) {
        const int kv0 = kt << 5;
        __syncthreads();
        {
            int row = tid >> 3, col = (tid & 7) * 8;
            __builtin_amdgcn_global_load_lds(
                (AS1 const void*)(kb + (size_t)(kv0 + row) * DK + col),
                (AS3 void*)(lK + w * 64 * 8), 16, 0, 0);
            u16x8 vv = *(const u16x8*)(vb + (size_t)(kv0 + row) * DK + col);
#pragma unroll
            for (int j = 0; j < 8; ++j)
                lVT[(col + j) * 32 + row] = vv[j];
        }
        __syncthreads();

        // S = (Q K^T) * scale, 16x32 per wave
        f32x4 sacc[2] = {};
#pragma unroll
        for (int nt = 0; nt < 2; ++nt)
#pragma unroll
            for (int kk = 0; kk < 2; ++kk) {
                bf16x8 kf = *(const bf16x8*)(lK + (nt * 16 + ccol) * DK + kk * 32 + kgrp);
                sacc[nt] = __builtin_amdgcn_mfma_f32_16x16x32_bf16(qa[kk], kf, sacc[nt], 0, 0, 0);
            }

        float p[2][4];
#pragma unroll
        for (int r = 0; r < 4; ++r) {
            int grow = crow + r;
            float s0 = sacc[0][r] * 0.125f;
            float s1 = sacc[1][r] * 0.125f;
            if (kv0 + ccol > grow) s0 = -1e30f;
            if (kv0 + 16 + ccol > grow) s1 = -1e30f;
            float mx = fmaxf(s0, s1);
#pragma unroll
            for (int off = 8; off; off >>= 1) mx = fmaxf(mx, __shfl_xor(mx, off));
            float mnew = fmaxf(mrow[r], mx);
            float p0 = __expf(s0 - mnew), p1 = __expf(s1 - mnew);
            float rs = p0 + p1;
#pragma unroll
            for (int off = 8; off; off >>= 1) rs += __shfl_xor(rs, off);
            float scale = __expf(mrow[r] - mnew);
            lrow[r] = lrow[r] * scale + rs;
            mrow[r] = mnew;
#pragma unroll
            for (int nt2 = 0; nt2 < 4; ++nt2) oacc[nt2][r] *= scale;
            p[0][r] = p0; p[1][r] = p1;
        }

        // P -> per-wave LDS (C-layout scatter), read back in A-frag layout
#pragma unroll
        for (int nt = 0; nt < 2; ++nt)
#pragma unroll
            for (int r = 0; r < 4; ++r)
                lP[w][((lane >> 4) * 4 + r) * 32 + nt * 16 + ccol] = f2bf(p[nt][r]);
        asm volatile("s_waitcnt lgkmcnt(0)" ::: "memory");
        bf16x8 pa = *(const bf16x8*)(&lP[w][(lane & 15) * 32 + kgrp]);

#pragma unroll
        for (int nt2 = 0; nt2 < 4; ++nt2) {
            bf16x8 vf = *(const bf16x8*)(lVT + (nt2 * 16 + ccol) * 32 + kgrp);
            oacc[nt2] = __builtin_amdgcn_mfma_f32_16x16x32_bf16(pa, vf, oacc[nt2], 0, 0, 0);
        }
    }

    // epilogue: normalize, store bf16 at [b*T+t][h*64+d]
    const int b = bh >> 4, h = bh & 15;
#pragma unroll
    for (int nt2 = 0; nt2 < 4; ++nt2)
#pragma unroll
        for (int r = 0; r < 4; ++r) {
            float val = oacc[nt2][r] / lrow[r];
            int trow = q0 + w * 16 + (lane >> 4) * 4 + r;
            o[(size_t)(b * T_LEN + trow) * D_DIM + h * DK + nt2 * 16 + ccol] = f2bf(val);
        }
}

// ---------------- launch ----------------
extern "C" void kernel_launch(void* const* d_in, const int* in_sizes, int n_in,
                              void* d_out, int out_size, void* d_ws, size_t ws_size,
                              hipStream_t stream) {
    const float* x  = (const float*)d_in[0];
    const float* Wq = (const float*)d_in[2];
    const float* Wk = (const float*)d_in[3];
    const float* Wv = (const float*)d_in[4];
    const float* Wo = (const float*)d_in[5];
    const float* bq = (const float*)d_in[6];
    const float* bk = (const float*)d_in[7];
    const float* bv = (const float*)d_in[8];
    const float* bo = (const float*)d_in[9];

    char* ws = (char*)d_ws;
    u16* xb   = (u16*)(ws);                    // 16 MB, reused as attn output
    u16* wqb  = (u16*)(ws + 16777216);
    u16* wkb  = (u16*)(ws + 18874368);
    u16* wvb  = (u16*)(ws + 20971520);
    u16* wob  = (u16*)(ws + 23068672);
    u16* qws  = (u16*)(ws + 25165824);
    u16* kws  = (u16*)(ws + 41943040);
    u16* vws  = (u16*)(ws + 58720256);
    u16* attnb = xb;

    cvt_bf16<<<4096, 256, 0, stream>>>(x, xb, 1048576);
    cvt_bf16<<<512, 256, 0, stream>>>(Wq, wqb, 131072);
    cvt_bf16<<<512, 256, 0, stream>>>(Wk, wkb, 131072);
    cvt_bf16<<<512, 256, 0, stream>>>(Wv, wvb, 131072);
    cvt_bf16<<<512, 256, 0, stream>>>(Wo, wob, 131072);

    dim3 ggrid(64, 8);
    gemm_bt<1><<<ggrid, 256, 0, stream>>>(xb, wqb, bq, qws, 8192, 1024, 1024);
    gemm_bt<1><<<ggrid, 256, 0, stream>>>(xb, wkb, bk, kws, 8192, 1024, 1024);
    gemm_bt<1><<<ggrid, 256, 0, stream>>>(xb, wvb, bv, vws, 8192, 1024, 1024);

    attn_fwd<<<dim3(32, 64), 256, 0, stream>>>(qws, kws, vws, attnb);

    gemm_bt<0><<<ggrid, 256, 0, stream>>>(attnb, wob, bo, d_out, 8192, 1024, 1024);
}

// Round 2
// 488.279 us; speedup vs baseline: 1.3545x; 1.3545x over previous
//
#include <hip/hip_runtime.h>
#include <hip/hip_bf16.h>

#define T_LEN 2048
#define D_DIM 1024
#define H_NUM 16
#define DK 64

typedef unsigned short u16;
typedef __bf16 bf16x8 __attribute__((ext_vector_type(8)));
typedef float f32x4 __attribute__((ext_vector_type(4)));
typedef u16 u16x8 __attribute__((ext_vector_type(8)));

#define AS1 __attribute__((address_space(1)))
#define AS3 __attribute__((address_space(3)))

__device__ __forceinline__ u16 f2bf(float f) {
    unsigned u = __builtin_bit_cast(unsigned, f);
    unsigned rounding = 0x7FFFu + ((u >> 16) & 1u);
    return (u16)((u + rounding) >> 16);
}

// ---------------- f32 -> bf16 conversion (8 elems / thread) ----------------
__global__ __launch_bounds__(256) void cvt_bf16(const float* __restrict__ in,
                                                u16* __restrict__ out, int n8) {
    int i = blockIdx.x * blockDim.x + threadIdx.x;
    if (i >= n8) return;
    const float4* p = (const float4*)in + (size_t)i * 2;
    float4 a = p[0], b = p[1];
    u16x8 r;
    r[0] = f2bf(a.x); r[1] = f2bf(a.y); r[2] = f2bf(a.z); r[3] = f2bf(a.w);
    r[4] = f2bf(b.x); r[5] = f2bf(b.y); r[6] = f2bf(b.z); r[7] = f2bf(b.w);
    *((u16x8*)out + i) = r;
}

// ---------------- GEMM: C[M,N] = A[M,K] * W[N,K]^T + bias ----------------
template <int MODE>
__global__ __launch_bounds__(256) void gemm_bt(const u16* __restrict__ A,
                                               const u16* __restrict__ W,
                                               const float* __restrict__ bias,
                                               void* __restrict__ Cout,
                                               int M, int N, int K) {
    __shared__ u16 lA[128 * 32];
    __shared__ u16 lB[128 * 32];
    const int tid = threadIdx.x;
    const int w = tid >> 6, lane = tid & 63;
    const int tm = blockIdx.x * 128;
    const int tn = blockIdx.y * 128;
    const int wm = (w >> 1) * 64, wn = (w & 1) * 64;
    const int kgrp = (lane >> 4) * 8;

    f32x4 acc[4][4] = {};

    for (int k0 = 0; k0 < K; k0 += 32) {
        __syncthreads();
#pragma unroll
        for (int r = 0; r < 2; ++r) {
            int c = r * 256 + tid;
            int row = c >> 2, col = (c & 3) * 8;
            const u16* ga = A + (size_t)(tm + row) * K + k0 + col;
            const u16* gb = W + (size_t)(tn + row) * K + k0 + col;
            __builtin_amdgcn_global_load_lds((AS1 const void*)ga,
                (AS3 void*)(lA + (size_t)(r * 256 + w * 64) * 8), 16, 0, 0);
            __builtin_amdgcn_global_load_lds((AS1 const void*)gb,
                (AS3 void*)(lB + (size_t)(r * 256 + w * 64) * 8), 16, 0, 0);
        }
        __syncthreads();

        bf16x8 af[4], bfr[4];
#pragma unroll
        for (int i = 0; i < 4; ++i) {
            af[i]  = *(const bf16x8*)(lA + (wm + i * 16 + (lane & 15)) * 32 + kgrp);
            bfr[i] = *(const bf16x8*)(lB + (wn + i * 16 + (lane & 15)) * 32 + kgrp);
        }
#pragma unroll
        for (int mi = 0; mi < 4; ++mi)
#pragma unroll
            for (int ni = 0; ni < 4; ++ni)
                acc[mi][ni] = __builtin_amdgcn_mfma_f32_16x16x32_bf16(
                    af[mi], bfr[ni], acc[mi][ni], 0, 0, 0);
    }

    const int crow0 = (lane >> 4) * 4;
    const int ccol = lane & 15;
#pragma unroll
    for (int mi = 0; mi < 4; ++mi) {
#pragma unroll
        for (int ni = 0; ni < 4; ++ni) {
            int n = tn + wn + ni * 16 + ccol;
            float bv = bias[n];
#pragma unroll
            for (int r = 0; r < 4; ++r) {
                int m = tm + wm + mi * 16 + crow0 + r;
                float val = acc[mi][ni][r] + bv;
                if (MODE == 0) {
                    ((float*)Cout)[(size_t)m * N + n] = val;
                } else {
                    int b = m >> 11, t = m & (T_LEN - 1);
                    int h = n >> 6, d = n & 63;
                    ((u16*)Cout)[((size_t)(b * H_NUM + h) * T_LEN + t) * DK + d] = f2bf(val);
                }
            }
        }
    }
}

// ---------------- Flash attention, causal ----------------
// grid: (T/128, B*H), block 256 (4 waves). Wave w owns Q rows
// {q0 + rg*64 + w*16 .. +16} for rg in {0,1}.  KV tile = 64 keys.
// All LDS buffers XOR-swizzled (16B-chunk granular) for conflict-free access.
__global__ __launch_bounds__(256) void attn_fwd(const u16* __restrict__ q,
                                                const u16* __restrict__ k,
                                                const u16* __restrict__ v,
                                                u16* __restrict__ o) {
    __shared__ u16 lK[64 * 64];    // [key][d], chunk ^= key&7
    __shared__ u16 lV[64 * 64];    // [d][key], key-block ^= (d^(d>>3))&7
    __shared__ u16 lP[4][16 * 64]; // per-wave [q][key], key-block ^= (q^(q>>3))&7

    const int tid = threadIdx.x, w = tid >> 6, lane = tid & 63;
    const int bh = blockIdx.y;
    const int q0 = blockIdx.x * 128;
    const u16* qb = q + (size_t)bh * T_LEN * DK;
    const u16* kb = k + (size_t)bh * T_LEN * DK;
    const u16* vb = v + (size_t)bh * T_LEN * DK;

    const int g = lane >> 4;       // k-group within MFMA
    const int ccol = lane & 15;

    // Q fragments for both row-groups (A-frag: row = lane&15)
    bf16x8 qa[2][2];
#pragma unroll
    for (int rg = 0; rg < 2; ++rg) {
        int arow = q0 + rg * 64 + w * 16 + ccol;
#pragma unroll
        for (int kk = 0; kk < 2; ++kk)
            qa[rg][kk] = *(const bf16x8*)(qb + (size_t)arow * DK + kk * 32 + g * 8);
    }

    f32x4 oacc[2][4] = {};
    float mrow[2][4], lrow[2][4];
#pragma unroll
    for (int rg = 0; rg < 2; ++rg)
#pragma unroll
        for (int r = 0; r < 4; ++r) { mrow[rg][r] = -1e30f; lrow[rg][r] = 0.f; }

    const int ntiles = 2 * (blockIdx.x + 1);
    for (int kt = 0; kt < ntiles; ++kt) {
        const int kv0 = kt << 6;
        __syncthreads();
        // ---- stage K via global_load_lds, source pre-swizzled (rule 21) ----
#pragma unroll
        for (int r2 = 0; r2 < 2; ++r2) {
            int c = r2 * 256 + tid;            // chunk index 0..511
            int row = c >> 3, ch = c & 7;
            const u16* gk = kb + (size_t)(kv0 + row) * DK + (ch ^ (row & 7)) * 8;
            __builtin_amdgcn_global_load_lds((AS1 const void*)gk,
                (AS3 void*)(lK + (size_t)(r2 * 256 + w * 64) * 8), 16, 0, 0);
        }
        // ---- stage V transposed: reg load + swizzled scalar scatter ----
#pragma unroll
        for (int r2 = 0; r2 < 2; ++r2) {
            int c = r2 * 256 + tid;
            int key = c >> 3, ch = c & 7;
            u16x8 v8 = *(const u16x8*)(vb + (size_t)(kv0 + key) * DK + ch * 8);
#pragma unroll
            for (int j = 0; j < 8; ++j) {
                int d = ch * 8 + j;
                lV[d * 64 + (key ^ ((j ^ ch) * 8))] = v8[j];
            }
        }
        __syncthreads();

        // ---- hoist V fragments (shared by both row-groups) ----
        bf16x8 vf[4][2];
#pragma unroll
        for (int nt2 = 0; nt2 < 4; ++nt2) {
            int swz = ((ccol & 7) ^ (nt2 * 2 + (ccol >> 3))) & 7;
#pragma unroll
            for (int kk2 = 0; kk2 < 2; ++kk2)
                vf[nt2][kk2] = *(const bf16x8*)(lV + (nt2 * 16 + ccol) * 64 +
                                                ((kk2 * 4 + g) ^ swz) * 8);
        }

#pragma unroll
        for (int rg = 0; rg < 2; ++rg) {
            const int rowbase = q0 + rg * 64 + w * 16;
            if (kv0 >= rowbase + 16) continue;  // tile fully masked for this group

            // S = Q K^T * scale   (16 q-rows x 64 keys)
            f32x4 sacc[4] = {};
#pragma unroll
            for (int nt = 0; nt < 4; ++nt) {
#pragma unroll
                for (int kk = 0; kk < 2; ++kk) {
                    bf16x8 kf = *(const bf16x8*)(lK + (nt * 16 + ccol) * 64 +
                                                 (((kk * 4 + g) ^ (ccol & 7)) * 8));
                    sacc[nt] = __builtin_amdgcn_mfma_f32_16x16x32_bf16(
                        qa[rg][kk], kf, sacc[nt], 0, 0, 0);
                }
            }

            // online softmax
            float p[4][4];
#pragma unroll
            for (int r = 0; r < 4; ++r) {
                int grow = rowbase + g * 4 + r;
                float s[4], mx = -1e30f;
#pragma unroll
                for (int nt = 0; nt < 4; ++nt) {
                    float sv = sacc[nt][r] * 0.125f;
                    if (kv0 + nt * 16 + ccol > grow) sv = -1e30f;
                    s[nt] = sv;
                    mx = fmaxf(mx, sv);
                }
#pragma unroll
                for (int off = 8; off; off >>= 1) mx = fmaxf(mx, __shfl_xor(mx, off));
                float mnew = fmaxf(mrow[rg][r], mx);
                float rs = 0.f;
#pragma unroll
                for (int nt = 0; nt < 4; ++nt) {
                    p[nt][r] = __expf(s[nt] - mnew);
                    rs += p[nt][r];
                }
#pragma unroll
                for (int off = 8; off; off >>= 1) rs += __shfl_xor(rs, off);
                float scale = __expf(mrow[rg][r] - mnew);
                lrow[rg][r] = lrow[rg][r] * scale + rs;
                mrow[rg][r] = mnew;
#pragma unroll
                for (int nt2 = 0; nt2 < 4; ++nt2) oacc[rg][nt2][r] *= scale;
            }

            // P -> per-wave LDS (swizzled), read back as A-frags
#pragma unroll
            for (int nt = 0; nt < 4; ++nt)
#pragma unroll
                for (int r = 0; r < 4; ++r) {
                    int qrow = g * 4 + r;
                    int swzq = ((qrow ^ (qrow >> 3)) & 7) * 8;
                    lP[w][qrow * 64 + ((nt * 16 + ccol) ^ swzq)] = f2bf(p[nt][r]);
                }
            asm volatile("s_waitcnt lgkmcnt(0)" ::: "memory");
            bf16x8 pa[2];
            {
                int swzr = (ccol ^ (ccol >> 3)) & 7;
#pragma unroll
                for (int kk2 = 0; kk2 < 2; ++kk2)
                    pa[kk2] = *(const bf16x8*)(&lP[w][ccol * 64 +
                                               ((kk2 * 4 + g) ^ swzr) * 8]);
            }
#pragma unroll
            for (int nt2 = 0; nt2 < 4; ++nt2)
#pragma unroll
                for (int kk2 = 0; kk2 < 2; ++kk2)
                    oacc[rg][nt2] = __builtin_amdgcn_mfma_f32_16x16x32_bf16(
                        pa[kk2], vf[nt2][kk2], oacc[rg][nt2], 0, 0, 0);
        }
    }

    // epilogue: normalize, store bf16 at [b*T+t][h*64+d]
    const int b = bh >> 4, h = bh & 15;
#pragma unroll
    for (int rg = 0; rg < 2; ++rg)
#pragma unroll
        for (int nt2 = 0; nt2 < 4; ++nt2)
#pragma unroll
            for (int r = 0; r < 4; ++r) {
                float val = oacc[rg][nt2][r] / lrow[rg][r];
                int trow = q0 + rg * 64 + w * 16 + g * 4 + r;
                o[(size_t)(b * T_LEN + trow) * D_DIM + h * DK + nt2 * 16 + ccol] = f2bf(val);
            }
}

// ---------------- launch ----------------
extern "C" void kernel_launch(void* const* d_in, const int* in_sizes, int n_in,
                              void* d_out, int out_size, void* d_ws, size_t ws_size,
                              hipStream_t stream) {
    const float* x  = (const float*)d_in[0];
    const float* Wq = (const float*)d_in[2];
    const float* Wk = (const float*)d_in[3];
    const float* Wv = (const float*)d_in[4];
    const float* Wo = (const float*)d_in[5];
    const float* bq = (const float*)d_in[6];
    const float* bk = (const float*)d_in[7];
    const float* bv = (const float*)d_in[8];
    const float* bo = (const float*)d_in[9];

    char* ws = (char*)d_ws;
    u16* xb   = (u16*)(ws);                    // 16 MB, reused as attn output
    u16* wqb  = (u16*)(ws + 16777216);
    u16* wkb  = (u16*)(ws + 18874368);
    u16* wvb  = (u16*)(ws + 20971520);
    u16* wob  = (u16*)(ws + 23068672);
    u16* qws  = (u16*)(ws + 25165824);
    u16* kws  = (u16*)(ws + 41943040);
    u16* vws  = (u16*)(ws + 58720256);
    u16* attnb = xb;

    cvt_bf16<<<4096, 256, 0, stream>>>(x, xb, 1048576);
    cvt_bf16<<<512, 256, 0, stream>>>(Wq, wqb, 131072);
    cvt_bf16<<<512, 256, 0, stream>>>(Wk, wkb, 131072);
    cvt_bf16<<<512, 256, 0, stream>>>(Wv, wvb, 131072);
    cvt_bf16<<<512, 256, 0, stream>>>(Wo, wob, 131072);

    dim3 ggrid(64, 8);
    gemm_bt<1><<<ggrid, 256, 0, stream>>>(xb, wqb, bq, qws, 8192, 1024, 1024);
    gemm_bt<1><<<ggrid, 256, 0, stream>>>(xb, wkb, bk, kws, 8192, 1024, 1024);
    gemm_bt<1><<<ggrid, 256, 0, stream>>>(xb, wvb, bv, vws, 8192, 1024, 1024);

    attn_fwd<<<dim3(16, 64), 256, 0, stream>>>(qws, kws, vws, attnb);

    gemm_bt<0><<<ggrid, 256, 0, stream>>>(attnb, wob, bo, d_out, 8192, 1024, 1024);
}

// Round 3
// 349.960 us; speedup vs baseline: 1.8898x; 1.3952x over previous
//
#include <hip/hip_runtime.h>
#include <hip/hip_bf16.h>

#define T_LEN 2048
#define D_DIM 1024
#define H_NUM 16
#define DK 64

typedef unsigned short u16;
typedef __bf16 bf16x8 __attribute__((ext_vector_type(8)));
typedef float f32x4 __attribute__((ext_vector_type(4)));
typedef u16 u16x8 __attribute__((ext_vector_type(8)));
typedef u16 u16x4 __attribute__((ext_vector_type(4)));

#define AS1 __attribute__((address_space(1)))
#define AS3 __attribute__((address_space(3)))

__device__ __forceinline__ u16 f2bf(float f) {
    unsigned u = __builtin_bit_cast(unsigned, f);
    unsigned rounding = 0x7FFFu + ((u >> 16) & 1u);
    return (u16)((u + rounding) >> 16);
}

// ---------------- f32 -> bf16 conversion (8 elems / thread) ----------------
__global__ __launch_bounds__(256) void cvt_bf16(const float* __restrict__ in,
                                                u16* __restrict__ out, int n8) {
    int i = blockIdx.x * blockDim.x + threadIdx.x;
    if (i >= n8) return;
    const float4* p = (const float4*)in + (size_t)i * 2;
    float4 a = p[0], b = p[1];
    u16x8 r;
    r[0] = f2bf(a.x); r[1] = f2bf(a.y); r[2] = f2bf(a.z); r[3] = f2bf(a.w);
    r[4] = f2bf(b.x); r[5] = f2bf(b.y); r[6] = f2bf(b.z); r[7] = f2bf(b.w);
    *((u16x8*)out + i) = r;
}

// 4 equal-size f32->bf16 segments (the four weight matrices), dst contiguous.
__global__ __launch_bounds__(256) void cvt4_bf16(const float* __restrict__ a,
                                                 const float* __restrict__ b,
                                                 const float* __restrict__ c,
                                                 const float* __restrict__ d,
                                                 u16* __restrict__ out, int n8per) {
    int s = blockIdx.y;
    const float* src = s == 0 ? a : (s == 1 ? b : (s == 2 ? c : d));
    int i = blockIdx.x * blockDim.x + threadIdx.x;
    if (i >= n8per) return;
    const float4* p = (const float4*)src + (size_t)i * 2;
    float4 x = p[0], y = p[1];
    u16x8 r;
    r[0] = f2bf(x.x); r[1] = f2bf(x.y); r[2] = f2bf(x.z); r[3] = f2bf(x.w);
    r[4] = f2bf(y.x); r[5] = f2bf(y.y); r[6] = f2bf(y.z); r[7] = f2bf(y.w);
    *((u16x8*)(out + (size_t)s * n8per * 8) + i) = r;
}

// ---------------- GEMM: C[M,N] = A[M,K] * W[N,K]^T + bias ----------------
// MODE 0: f32 row-major store.  MODE 1: bf16 store permuted to [mtx][B,H,T,DK]
// (N may span 3 concatenated weight matrices; bias picked per 1024-panel).
template <int MODE>
__global__ __launch_bounds__(256) void gemm_bt(const u16* __restrict__ A,
                                               const u16* __restrict__ W,
                                               const float* __restrict__ b0,
                                               const float* __restrict__ b1,
                                               const float* __restrict__ b2,
                                               void* __restrict__ Cout,
                                               int M, int N, int K) {
    __shared__ u16 lA[128 * 32];
    __shared__ u16 lB[128 * 32];
    const int tid = threadIdx.x;
    const int w = tid >> 6, lane = tid & 63;
    const int tm = blockIdx.x * 128;
    const int tn = blockIdx.y * 128;
    const int wm = (w >> 1) * 64, wn = (w & 1) * 64;
    const int kgrp = (lane >> 4) * 8;

    f32x4 acc[4][4] = {};

    for (int k0 = 0; k0 < K; k0 += 32) {
        __syncthreads();
#pragma unroll
        for (int r = 0; r < 2; ++r) {
            int c = r * 256 + tid;
            int row = c >> 2, col = (c & 3) * 8;
            const u16* ga = A + (size_t)(tm + row) * K + k0 + col;
            const u16* gb = W + (size_t)(tn + row) * K + k0 + col;
            __builtin_amdgcn_global_load_lds((AS1 const void*)ga,
                (AS3 void*)(lA + (size_t)(r * 256 + w * 64) * 8), 16, 0, 0);
            __builtin_amdgcn_global_load_lds((AS1 const void*)gb,
                (AS3 void*)(lB + (size_t)(r * 256 + w * 64) * 8), 16, 0, 0);
        }
        __syncthreads();

        bf16x8 af[4], bfr[4];
#pragma unroll
        for (int i = 0; i < 4; ++i) {
            af[i]  = *(const bf16x8*)(lA + (wm + i * 16 + (lane & 15)) * 32 + kgrp);
            bfr[i] = *(const bf16x8*)(lB + (wn + i * 16 + (lane & 15)) * 32 + kgrp);
        }
#pragma unroll
        for (int mi = 0; mi < 4; ++mi)
#pragma unroll
            for (int ni = 0; ni < 4; ++ni)
                acc[mi][ni] = __builtin_amdgcn_mfma_f32_16x16x32_bf16(
                    af[mi], bfr[ni], acc[mi][ni], 0, 0, 0);
    }

    const int mtx = tn >> 10;                       // which weight panel
    const float* bp = mtx == 0 ? b0 : (mtx == 1 ? b1 : b2);
    const int crow0 = (lane >> 4) * 4;
    const int ccol = lane & 15;
#pragma unroll
    for (int mi = 0; mi < 4; ++mi) {
#pragma unroll
        for (int ni = 0; ni < 4; ++ni) {
            int n = tn + wn + ni * 16 + ccol;
            float bv = bp[n & 1023];
#pragma unroll
            for (int r = 0; r < 4; ++r) {
                int m = tm + wm + mi * 16 + crow0 + r;
                float val = acc[mi][ni][r] + bv;
                if (MODE == 0) {
                    ((float*)Cout)[(size_t)m * N + n] = val;
                } else {
                    int b = m >> 11, t = m & (T_LEN - 1);
                    int nn = n & 1023;
                    int h = nn >> 6, d = nn & 63;
                    ((u16*)Cout)[(size_t)mtx * 8388608 +
                                 ((size_t)(b * H_NUM + h) * T_LEN + t) * DK + d] = f2bf(val);
                }
            }
        }
    }
}

// ---------------- Flash attention, causal, load-balanced + pipelined --------
// grid (8, B*H), block 256 (4 waves). Block bx handles q-block pair
// {bx, 15-bx}: total work = 34 KV-tiles for EVERY block (perfect balance).
// Double-buffered lK/lV; K via global_load_lds (pre-swizzled source),
// V via reg-stage + 4x4 transpose + swizzled ds_write_b64 (bank floor).
// ONE barrier per KV tile; next tile's loads issued before compute.
__global__ __launch_bounds__(256) void attn_fwd(const u16* __restrict__ q,
                                                const u16* __restrict__ k,
                                                const u16* __restrict__ v,
                                                u16* __restrict__ o) {
    __shared__ u16 lK[2][64 * 64];   // [key][d], 16B-window ^= key&7
    __shared__ u16 lV[2][64 * 64];   // [d][key], 16B-window ^= (d>>1)&7
    __shared__ u16 lP[4][16 * 64];   // per-wave P roundtrip (swizzled)

    const int tid = threadIdx.x, w = tid >> 6, lane = tid & 63;
    const int bh = blockIdx.y;
    const u16* qb = q + (size_t)bh * T_LEN * DK;
    const u16* kb = k + (size_t)bh * T_LEN * DK;
    const u16* vb = v + (size_t)bh * T_LEN * DK;

    const int g = lane >> 4;       // k-group within MFMA
    const int ccol = lane & 15;
    const int kg = tid >> 4;       // V-stage: key group (4 keys)
    const int dc = tid & 15;       // V-stage: d group (4 d)
    const int b_ = bh >> 4, h_ = bh & 15;

    for (int seg = 0; seg < 2; ++seg) {
        const int qblk = seg ? (15 - (int)blockIdx.x) : (int)blockIdx.x;
        const int q0 = qblk * 128;
        const int ntiles = 2 * qblk + 2;    // always even

        // Q fragments (A-frag: row = lane&15)
        bf16x8 qa[2][2];
#pragma unroll
        for (int rg = 0; rg < 2; ++rg) {
            int arow = q0 + rg * 64 + w * 16 + ccol;
#pragma unroll
            for (int kk = 0; kk < 2; ++kk)
                qa[rg][kk] = *(const bf16x8*)(qb + (size_t)arow * DK + kk * 32 + g * 8);
        }

        f32x4 oacc[2][4] = {};
        float mrow[2][4], lrow[2][4];
#pragma unroll
        for (int rg = 0; rg < 2; ++rg)
#pragma unroll
            for (int r = 0; r < 4; ++r) { mrow[rg][r] = -1e30f; lrow[rg][r] = 0.f; }

        // ---- prologue: issue tile 0 (buffer 0) ----
        u16x4 vr[4];
#pragma unroll
        for (int r2 = 0; r2 < 2; ++r2) {
            int c = r2 * 256 + tid, row = c >> 3, ch = c & 7;
            __builtin_amdgcn_global_load_lds(
                (AS1 const void*)(kb + (size_t)row * DK + (ch ^ (row & 7)) * 8),
                (AS3 void*)(&lK[0][(r2 * 256 + w * 64) * 8]), 16, 0, 0);
        }
#pragma unroll
        for (int i = 0; i < 4; ++i)
            vr[i] = *(const u16x4*)(vb + (size_t)(kg * 4 + i) * DK + dc * 4);

        for (int kt = 0; kt < ntiles; ++kt) {
            const int bf = kt & 1;
            const int kv0 = kt << 6;
            asm volatile("s_waitcnt vmcnt(0)" ::: "memory");
            // scatter V(kt) -> lV[bf] (transposed, swizzled, b64 writes)
#pragma unroll
            for (int j = 0; j < 4; ++j) {
                int d = dc * 4 + j;
                u16x4 t4;
                t4[0] = vr[0][j]; t4[1] = vr[1][j]; t4[2] = vr[2][j]; t4[3] = vr[3][j];
                *(u16x4*)(&lV[bf][d * 64 + (((kg >> 1) ^ ((d >> 1) & 7)) * 8 + (kg & 1) * 4)]) = t4;
            }
            __syncthreads();

            // issue tile kt+1 into buffers bf^1 (hidden under compute)
            if (kt + 1 < ntiles) {
                const int kvn = (kt + 1) << 6;
#pragma unroll
                for (int r2 = 0; r2 < 2; ++r2) {
                    int c = r2 * 256 + tid, row = c >> 3, ch = c & 7;
                    __builtin_amdgcn_global_load_lds(
                        (AS1 const void*)(kb + (size_t)(kvn + row) * DK + (ch ^ (row & 7)) * 8),
                        (AS3 void*)(&lK[bf ^ 1][(r2 * 256 + w * 64) * 8]), 16, 0, 0);
                }
#pragma unroll
                for (int i = 0; i < 4; ++i)
                    vr[i] = *(const u16x4*)(vb + (size_t)(kvn + kg * 4 + i) * DK + dc * 4);
            }

            // hoist V fragments (shared by both row-groups)
            bf16x8 vf[4][2];
            const int vsw = (ccol >> 1) & 7;
#pragma unroll
            for (int nt2 = 0; nt2 < 4; ++nt2)
#pragma unroll
                for (int kk2 = 0; kk2 < 2; ++kk2)
                    vf[nt2][kk2] = *(const bf16x8*)(&lV[bf][(nt2 * 16 + ccol) * 64 +
                                                    (((kk2 * 4 + g) ^ vsw) * 8)]);

#pragma unroll
            for (int rg = 0; rg < 2; ++rg) {
                const int rowbase = q0 + rg * 64 + w * 16;
                if (kv0 >= rowbase + 16) continue;  // fully masked for this wave

                f32x4 sacc[4] = {};
#pragma unroll
                for (int nt = 0; nt < 4; ++nt)
#pragma unroll
                    for (int kk = 0; kk < 2; ++kk) {
                        bf16x8 kf = *(const bf16x8*)(&lK[bf][(nt * 16 + ccol) * 64 +
                                                     (((kk * 4 + g) ^ (ccol & 7)) * 8)]);
                        sacc[nt] = __builtin_amdgcn_mfma_f32_16x16x32_bf16(
                            qa[rg][kk], kf, sacc[nt], 0, 0, 0);
                    }

                const bool full = (kv0 + 63) <= rowbase;  // wave-uniform
                float p[4][4];
#pragma unroll
                for (int r = 0; r < 4; ++r) {
                    int grow = rowbase + g * 4 + r;
                    float s[4], mx = -1e30f;
#pragma unroll
                    for (int nt = 0; nt < 4; ++nt) {
                        float sv = sacc[nt][r] * 0.125f;
                        if (!full && (kv0 + nt * 16 + ccol > grow)) sv = -1e30f;
                        s[nt] = sv;
                        mx = fmaxf(mx, sv);
                    }
#pragma unroll
                    for (int off = 8; off; off >>= 1) mx = fmaxf(mx, __shfl_xor(mx, off));
                    float mnew = fmaxf(mrow[rg][r], mx);
                    float rs = 0.f;
#pragma unroll
                    for (int nt = 0; nt < 4; ++nt) {
                        p[nt][r] = __expf(s[nt] - mnew);
                        rs += p[nt][r];
                    }
#pragma unroll
                    for (int off = 8; off; off >>= 1) rs += __shfl_xor(rs, off);
                    float scale = __expf(mrow[rg][r] - mnew);
                    lrow[rg][r] = lrow[rg][r] * scale + rs;
                    mrow[rg][r] = mnew;
#pragma unroll
                    for (int nt2 = 0; nt2 < 4; ++nt2) oacc[rg][nt2][r] *= scale;
                }

                // P -> per-wave LDS (swizzled), read back as A-frags
#pragma unroll
                for (int nt = 0; nt < 4; ++nt)
#pragma unroll
                    for (int r = 0; r < 4; ++r) {
                        int qrow = g * 4 + r;
                        int swzq = ((qrow ^ (qrow >> 3)) & 7) * 8;
                        lP[w][qrow * 64 + ((nt * 16 + ccol) ^ swzq)] = f2bf(p[nt][r]);
                    }
                asm volatile("s_waitcnt lgkmcnt(0)" ::: "memory");
                bf16x8 pa[2];
                {
                    int swzr = (ccol ^ (ccol >> 3)) & 7;
#pragma unroll
                    for (int kk2 = 0; kk2 < 2; ++kk2)
                        pa[kk2] = *(const bf16x8*)(&lP[w][ccol * 64 +
                                                   ((kk2 * 4 + g) ^ swzr) * 8]);
                }
#pragma unroll
                for (int nt2 = 0; nt2 < 4; ++nt2)
#pragma unroll
                    for (int kk2 = 0; kk2 < 2; ++kk2)
                        oacc[rg][nt2] = __builtin_amdgcn_mfma_f32_16x16x32_bf16(
                            pa[kk2], vf[nt2][kk2], oacc[rg][nt2], 0, 0, 0);
            }
            // single barrier per tile: buffers alternate; every wave drains its
            // own vmcnt before the next barrier, so no second barrier needed.
        }

        // epilogue: normalize, store bf16 at [b*T+t][h*64+d]
#pragma unroll
        for (int rg = 0; rg < 2; ++rg)
#pragma unroll
            for (int nt2 = 0; nt2 < 4; ++nt2)
#pragma unroll
                for (int r = 0; r < 4; ++r) {
                    float val = oacc[rg][nt2][r] / lrow[rg][r];
                    int trow = q0 + rg * 64 + w * 16 + g * 4 + r;
                    o[(size_t)(b_ * T_LEN + trow) * D_DIM + h_ * DK + nt2 * 16 + ccol] = f2bf(val);
                }
    }
}

// ---------------- launch ----------------
extern "C" void kernel_launch(void* const* d_in, const int* in_sizes, int n_in,
                              void* d_out, int out_size, void* d_ws, size_t ws_size,
                              hipStream_t stream) {
    const float* x  = (const float*)d_in[0];
    const float* Wq = (const float*)d_in[2];
    const float* Wk = (const float*)d_in[3];
    const float* Wv = (const float*)d_in[4];
    const float* Wo = (const float*)d_in[5];
    const float* bq = (const float*)d_in[6];
    const float* bk = (const float*)d_in[7];
    const float* bv = (const float*)d_in[8];
    const float* bo = (const float*)d_in[9];

    char* ws = (char*)d_ws;
    u16* xb   = (u16*)(ws);                    // 16 MB, reused as attn output
    u16* wqb  = (u16*)(ws + 16777216);         // wq|wk|wv|wo contiguous 2MB each
    u16* wob  = (u16*)(ws + 23068672);
    u16* qws  = (u16*)(ws + 25165824);         // q|k|v contiguous 16MB each
    u16* kws  = (u16*)(ws + 41943040);
    u16* vws  = (u16*)(ws + 58720256);
    u16* attnb = xb;

    cvt_bf16<<<4096, 256, 0, stream>>>(x, xb, 1048576);
    cvt4_bf16<<<dim3(512, 4), 256, 0, stream>>>(Wq, Wk, Wv, Wo, wqb, 131072);

    // fused QKV projection: N = 3072 (wq|wk|wv panels)
    gemm_bt<1><<<dim3(64, 24), 256, 0, stream>>>(xb, wqb, bq, bk, bv, qws, 8192, 3072, 1024);

    attn_fwd<<<dim3(8, 64), 256, 0, stream>>>(qws, kws, vws, attnb);

    gemm_bt<0><<<dim3(64, 8), 256, 0, stream>>>(attnb, wob, bo, bo, bo, d_out, 8192, 1024, 1024);
}